// Round 12
// baseline (7258.350 us; speedup 1.0000x reference)
//
#include <hip/hip_runtime.h>
#include <math.h>

#define NTHR 512
typedef unsigned long long u64;

// ---------------------------------------------------------------- helpers
__device__ __forceinline__ void st_uc(float* p, float v) {
    asm volatile("global_store_dword %0, %1, off sc0 sc1" :: "v"(p), "v"(v) : "memory");
}
#define LGKM0_BAR do { \
    asm volatile("s_waitcnt lgkmcnt(0)" ::: "memory"); \
    __builtin_amdgcn_s_barrier(); \
} while (0)

__device__ __forceinline__ float comp4(float4 v, int b) {
    float xy = (b & 1) ? v.y : v.x;
    float zw = (b & 1) ? v.w : v.z;
    return (b & 2) ? zw : xy;
}
#define RED4(a, d) do { \
    a.x += __shfl_xor(a.x, d); a.y += __shfl_xor(a.y, d); \
    a.z += __shfl_xor(a.z, d); a.w += __shfl_xor(a.w, d); } while (0)

// ---------------------------------------------------------------- init
// hp/gp: 2 slots x 32 batches x 1024 cols of (step:u32 | value:f32) pairs.
__global__ void init_kernel(u64* hp, u64* gp) {
    int i = blockIdx.x * blockDim.x + threadIdx.x;
    if (i < 65536) {
        __hip_atomic_store(hp + i, 0xFFFFFFFF00000000ull, __ATOMIC_RELAXED, __HIP_MEMORY_SCOPE_AGENT);
        __hip_atomic_store(gp + i, 0xFFFFFFFE00000000ull, __ATOMIC_RELAXED, __HIP_MEMORY_SCOPE_AGENT);
    }
}

// ---------------------------------------------------------------- xb = x @ b
__global__ __launch_bounds__(256) void xb_gemm(const float* __restrict__ X,
                                               const float* __restrict__ Bw,
                                               float* __restrict__ XB) {
    __shared__ float xs[16][132];
    __shared__ float bs[16][132];
    const int bm = blockIdx.x >> 3;
    const int bn = blockIdx.x & 7;
    const int m0 = bm * 128, n0 = bn * 128;
    const int tid = threadIdx.x;
    const int tx = tid & 15, ty = tid >> 4;
    float acc[8][8];
#pragma unroll
    for (int i = 0; i < 8; ++i)
#pragma unroll
        for (int j = 0; j < 8; ++j) acc[i][j] = 0.f;

    for (int k0 = 0; k0 < 1024; k0 += 16) {
#pragma unroll
        for (int p = 0; p < 2; ++p) {
            int f = tid + p * 256;
            int m = f >> 2, kq = f & 3;
            float4 v = *(const float4*)&X[(size_t)(m0 + m) * 1024 + k0 + kq * 4];
            xs[kq * 4 + 0][m] = v.x; xs[kq * 4 + 1][m] = v.y;
            xs[kq * 4 + 2][m] = v.z; xs[kq * 4 + 3][m] = v.w;
        }
#pragma unroll
        for (int p = 0; p < 2; ++p) {
            int f = tid + p * 256;
            int k = f >> 5, n = (f & 31) * 4;
            float4 v = *(const float4*)&Bw[(size_t)(k0 + k) * 1024 + n0 + n];
            *(float4*)&bs[k][n] = v;
        }
        __syncthreads();
#pragma unroll
        for (int k = 0; k < 16; ++k) {
            float xv[8], bv[8];
            *(float4*)&xv[0] = *(const float4*)&xs[k][ty * 8];
            *(float4*)&xv[4] = *(const float4*)&xs[k][ty * 8 + 4];
            *(float4*)&bv[0] = *(const float4*)&bs[k][tx * 8];
            *(float4*)&bv[4] = *(const float4*)&bs[k][tx * 8 + 4];
#pragma unroll
            for (int i = 0; i < 8; ++i)
#pragma unroll
                for (int j = 0; j < 8; ++j) acc[i][j] += xv[i] * bv[j];
        }
        __syncthreads();
    }
#pragma unroll
    for (int i = 0; i < 8; ++i)
#pragma unroll
        for (int j = 0; j < 8; j += 4) {
            float4 v = make_float4(acc[i][j], acc[i][j + 1], acc[i][j + 2], acc[i][j + 3]);
            *(float4*)&XB[(size_t)(m0 + ty * 8 + i) * 1024 + n0 + tx * 8 + j] = v;
        }
}

// ---------------------------------------------------------------- persistent scan
// 256 WGs = 2 streams x 4 bg(4 batches) x 64 slices (16 cols). In-band pairs
// (r10/r11, proven). New: full-k-per-wave compute (wave owns 2 cols; finishes
// its outputs intra-wave via f4 butterfly), inline publish at end of compute,
// ping-pong staging [k][b]-f4 XOR-swizzled, ONE barrier per sub-phase.
__global__ __launch_bounds__(NTHR, 1) void scan_kernel(
    const float* __restrict__ A, const float* __restrict__ CTm,
    float* __restrict__ XBH, u64* __restrict__ hp, u64* __restrict__ gp,
    float* __restrict__ ht_out, float* __restrict__ ct_out) {
    extern __shared__ float lds[];
    float* a_lf  = lds;                    // 16 cols x 256 f4, swizzled (64KB)
    float* ct_lf = lds + 16384;            // (64KB)
    float* stg0f = lds + 32768;            // 1024 f4 [k][b], swizzled (16KB)
    float* stg1f = lds + 36864;            // (16KB)  -> 160KiB total
    const float4* a_l4  = (const float4*)a_lf;
    const float4* ct_l4 = (const float4*)ct_lf;

    const int wg  = blockIdx.x;
    const int bg0 = wg >> 6;               // 0..3
    const int bg1 = bg0 + 4;               // 4..7
    const int sg  = wg & 63;
    const int c0wg = sg * 16;
    const int tid = threadIdx.x;

    // ---- one-time weight preload: cols c0wg..+15, col-major f4-of-k, swizzled
    {
        const int c = tid & 15, i0 = tid >> 4;
        for (int i = i0; i < 1024; i += 32) {
            int fi = (c << 10) + ((((i >> 2) ^ ((i >> 6) & 7))) << 2) + (i & 3);
            a_lf[fi]  = A[(size_t)i * 1024 + c0wg + c];
            ct_lf[fi] = CTm[(size_t)i * 1024 + c0wg + c];
        }
    }

    const int L  = tid & 63;
    const int w  = tid >> 6;
    const int ks = L & 7;                  // staging swizzle key
    const int kw = (L >> 2) & 7;           // weight key, phase A
    const int gt = L >> 4;                 // phase-B gate 0..3
    const int kb = ((gt << 2) + ((L & 15) >> 2)) & 7;   // weight key, phase B
    const int lc0 = 2 * w, lc1 = 2 * w + 1;
    const bool pub = (L < 8);
    const int p_b = L & 3;
    const int p_c = (L >> 2) & 1;
    const int p_col = c0wg + 2 * w + p_c;

    float creg0 = 0.f, creg1 = 0.f;        // publisher lanes: cell state per stream
    float xb0 = 0.f, xb1 = 0.f;
    u64 qpf[8];

    auto issue_pf = [&](const u64* base) {
#pragma unroll
        for (int j = 0; j < 8; ++j)
            qpf[j] = __hip_atomic_load(base + tid + 512 * j, __ATOMIC_RELAXED,
                                       __HIP_MEMORY_SCOPE_AGENT);
    };

    // validate prefetched pairs, unpack into stg (swizzled [k][b])
    auto stage = [&](const u64* base, unsigned expect, float* stgbuf) {
        u64 q[8];
#pragma unroll
        for (int j = 0; j < 8; ++j) q[j] = qpf[j];
        for (;;) {
            bool ok = true;
#pragma unroll
            for (int j = 0; j < 8; ++j) ok &= ((unsigned)(q[j] >> 32) == expect);
            if (!__any(!ok)) break;
            __builtin_amdgcn_s_sleep(1);
#pragma unroll
            for (int j = 0; j < 8; ++j)
                q[j] = __hip_atomic_load(base + tid + 512 * j, __ATOMIC_RELAXED,
                                         __HIP_MEMORY_SCOPE_AGENT);
        }
#pragma unroll
        for (int j = 0; j < 8; ++j) {
            int p = tid + 512 * j;
            int k = p & 1023, b = p >> 10;
            int s = k ^ ((k >> 4) & 7);
            stgbuf[(s << 2) + b] = __uint_as_float((unsigned)q[j]);
        }
    };

    // phase A core: full 1024-dot for cols lc0/lc1, all 4 batches -> r0, r1
    auto computeA = [&](const float* stgbuf, float4& r0, float4& r1) {
        const float4* hb = (const float4*)stgbuf + (L << 4);
        const float4* wa = a_l4 + lc0 * 256;
        const float4* wb = a_l4 + lc1 * 256;
        float4 a0 = make_float4(0.f, 0.f, 0.f, 0.f), a1 = a0;
#pragma unroll
        for (int ii = 0; ii < 4; ++ii) {
            float4 w0 = wa[((L << 2) + ii) ^ kw];
            float4 w1 = wb[((L << 2) + ii) ^ kw];
            float4 h0 = hb[(ii * 4 + 0) ^ ks];
            float4 h1 = hb[(ii * 4 + 1) ^ ks];
            float4 h2 = hb[(ii * 4 + 2) ^ ks];
            float4 h3 = hb[(ii * 4 + 3) ^ ks];
            a0.x += h0.x*w0.x + h1.x*w0.y + h2.x*w0.z + h3.x*w0.w;
            a0.y += h0.y*w0.x + h1.y*w0.y + h2.y*w0.z + h3.y*w0.w;
            a0.z += h0.z*w0.x + h1.z*w0.y + h2.z*w0.z + h3.z*w0.w;
            a0.w += h0.w*w0.x + h1.w*w0.y + h2.w*w0.z + h3.w*w0.w;
            a1.x += h0.x*w1.x + h1.x*w1.y + h2.x*w1.z + h3.x*w1.w;
            a1.y += h0.y*w1.x + h1.y*w1.y + h2.y*w1.z + h3.y*w1.w;
            a1.z += h0.z*w1.x + h1.z*w1.y + h2.z*w1.z + h3.z*w1.w;
            a1.w += h0.w*w1.x + h1.w*w1.y + h2.w*w1.z + h3.w*w1.w;
        }
        RED4(a0, 1); RED4(a1, 1); RED4(a0, 2); RED4(a1, 2);
        RED4(a0, 4); RED4(a1, 4); RED4(a0, 8); RED4(a1, 8);
        RED4(a0, 16); RED4(a1, 16); RED4(a0, 32); RED4(a1, 32);
        r0 = a0; r1 = a1;
    };
    // phase B core: per-gate 256-dots (gate = L>>4), reduced over chunk L&15
    auto computeB = [&](const float* stgbuf, float4& r0, float4& r1) {
        const float4* gb = (const float4*)stgbuf + (gt << 8) + ((L & 15) << 4);
        const float4* wa = ct_l4 + lc0 * 256 + (gt << 6);
        const float4* wb = ct_l4 + lc1 * 256 + (gt << 6);
        float4 a0 = make_float4(0.f, 0.f, 0.f, 0.f), a1 = a0;
#pragma unroll
        for (int ii = 0; ii < 4; ++ii) {
            int wi = ((L & 15) << 2) + ii;
            float4 w0 = wa[wi ^ kb];
            float4 w1 = wb[wi ^ kb];
            float4 h0 = gb[(ii * 4 + 0) ^ ks];
            float4 h1 = gb[(ii * 4 + 1) ^ ks];
            float4 h2 = gb[(ii * 4 + 2) ^ ks];
            float4 h3 = gb[(ii * 4 + 3) ^ ks];
            a0.x += h0.x*w0.x + h1.x*w0.y + h2.x*w0.z + h3.x*w0.w;
            a0.y += h0.y*w0.x + h1.y*w0.y + h2.y*w0.z + h3.y*w0.w;
            a0.z += h0.z*w0.x + h1.z*w0.y + h2.z*w0.z + h3.z*w0.w;
            a0.w += h0.w*w0.x + h1.w*w0.y + h2.w*w0.z + h3.w*w0.w;
            a1.x += h0.x*w1.x + h1.x*w1.y + h2.x*w1.z + h3.x*w1.w;
            a1.y += h0.y*w1.x + h1.y*w1.y + h2.y*w1.z + h3.y*w1.w;
            a1.z += h0.z*w1.x + h1.z*w1.y + h2.z*w1.z + h3.z*w1.w;
            a1.w += h0.w*w1.x + h1.w*w1.y + h2.w*w1.z + h3.w*w1.w;
        }
        RED4(a0, 1); RED4(a1, 1); RED4(a0, 2); RED4(a1, 2);
        RED4(a0, 4); RED4(a1, 4); RED4(a0, 8); RED4(a1, 8);
        r0 = a0; r1 = a1;
    };

    // sub-phases: [stage -> BAR -> compute -> inline publish -> prefetch next]
    auto subA = [&](u64* base, unsigned expect, float* stgbuf, int bgx, float xbv,
                    u64* pubbase, int t, const u64* pfbase) {
        stage(base, expect, stgbuf);
        LGKM0_BAR;
        float4 r0, r1;
        computeA(stgbuf, r0, r1);
        if (pub) {
            float4 accP = p_c ? r1 : r0;
            float d = comp4(accP, p_b);
            u64 pk = ((u64)(unsigned)t << 32) | (u64)__float_as_uint(d * xbv);
            __hip_atomic_store(pubbase + (size_t)(bgx * 4 + p_b) * 1024 + p_col,
                               pk, __ATOMIC_RELAXED, __HIP_MEMORY_SCOPE_AGENT);
        }
        issue_pf(pfbase);
    };
    auto subB = [&](u64* base, unsigned expect, float* stgbuf, int bgx, float& creg,
                    u64* pubbase, int t, const u64* pfbase) {
        stage(base, expect, stgbuf);
        LGKM0_BAR;
        float4 r0, r1;
        computeB(stgbuf, r0, r1);
        float s0 = comp4(r0, L & 3);
        float s1 = comp4(r1, L & 3);
        int src = L & 15;
        float i0v = __shfl(s0, src + 16), g0v = __shfl(s0, src + 32), o0v = __shfl(s0, src + 48);
        float i1v = __shfl(s1, src + 16), g1v = __shfl(s1, src + 32), o1v = __shfl(s1, src + 48);
        if (pub) {
            float q0 = p_c ? s1 : s0;       // f gate (own, gt==0 for L<8)
            float q1 = p_c ? i1v : i0v;     // i
            float q2 = p_c ? g1v : g0v;     // g
            float q3 = p_c ? o1v : o0v;     // o
            float ft = 1.f / (1.f + __expf(-q0));
            float it = 1.f / (1.f + __expf(-q1));
            float gg = tanhf(q2);
            float ot = 1.f / (1.f + __expf(-q3));
            creg = ft * creg + it * gg;
            float hv = ot * tanhf(creg);
            int bglob = bgx * 4 + p_b;
            u64 pk = ((u64)(unsigned)t << 32) | (u64)__float_as_uint(hv);
            __hip_atomic_store(pubbase + (size_t)bglob * 1024 + p_col,
                               pk, __ATOMIC_RELAXED, __HIP_MEMORY_SCOPE_AGENT);
            st_uc(XBH + ((size_t)bglob * 512 + t) * 1024 + p_col, hv);
            if (t == 511) {
                st_uc(ht_out + (size_t)bglob * 1024 + p_col, hv);
                st_uc(ct_out + (size_t)bglob * 1024 + p_col, creg);
            }
        }
        issue_pf(pfbase);
    };

    __syncthreads();                       // weights ready
    issue_pf(hp + 32768 + (size_t)bg0 * 4096);   // A0(0): hp slot 1

    for (int k = 0; k < 512; ++k) {
        const unsigned expA = (unsigned)(k - 1);
        const unsigned expB = (unsigned)k;
        if (pub) {                          // xb for this iter's publishes
            xb0 = XBH[((size_t)(bg0 * 4 + p_b) * 512 + k) * 1024 + p_col];
            xb1 = XBH[((size_t)(bg1 * 4 + p_b) * 512 + k) * 1024 + p_col];
        }
        const size_t hsl = (size_t)((k + 1) & 1) * 32768;
        const size_t gsl = (size_t)(k & 1) * 32768;
        // A0(k): consume h0(k-1); publish g0(k); prefetch A1 = h1(k-1)
        subA(hp + hsl + (size_t)bg0 * 4096, expA, stg0f, bg0, xb0,
             gp + gsl, k, hp + hsl + (size_t)bg1 * 4096);
        // A1(k): consume h1(k-1); publish g1(k); prefetch B0 = g0(k)
        subA(hp + hsl + (size_t)bg1 * 4096, expA, stg1f, bg1, xb1,
             gp + gsl, k, gp + gsl + (size_t)bg0 * 4096);
        // B0(k): consume g0(k); publish h0(k); prefetch B1 = g1(k)
        subB(gp + gsl + (size_t)bg0 * 4096, expB, stg0f, bg0, creg0,
             hp + (size_t)(k & 1) * 32768, k, gp + gsl + (size_t)bg1 * 4096);
        // B1(k): consume g1(k); publish h1(k); prefetch A0(k+1) = h0(k)
        subB(gp + gsl + (size_t)bg1 * 4096, expB, stg1f, bg1, creg1,
             hp + (size_t)(k & 1) * 32768, k, hp + (size_t)(k & 1) * 32768 + (size_t)bg0 * 4096);
    }
}

// ---------------------------------------------------------------- launch
extern "C" void kernel_launch(void* const* d_in, const int* in_sizes, int n_in,
                              void* d_out, int out_size, void* d_ws, size_t ws_size,
                              hipStream_t stream) {
    const float* X   = (const float*)d_in[0];
    const float* A   = (const float*)d_in[1];
    const float* Bw  = (const float*)d_in[2];
    const float* CTm = (const float*)d_in[3];

    float* out    = (float*)d_out;
    float* XBH    = out;                                  // xb in, hidden_seq out
    float* ht_out = out + (size_t)32 * 512 * 1024;
    float* ct_out = ht_out + 32 * 1024;

    u64* hp = (u64*)d_ws;                                 // 65536 pairs (512KB)
    u64* gp = hp + 65536;                                 // 65536 pairs (512KB)

    (void)hipFuncSetAttribute((const void*)scan_kernel,
                              hipFuncAttributeMaxDynamicSharedMemorySize, 163840);

    init_kernel<<<dim3(256), dim3(256), 0, stream>>>(hp, gp);
    xb_gemm<<<dim3(1024), dim3(256), 0, stream>>>(X, Bw, XBH);
    scan_kernel<<<dim3(256), dim3(NTHR), 163840, stream>>>(A, CTm, XBH, hp, gp,
                                                           ht_out, ct_out);
}

// Round 13
// 4579.699 us; speedup vs baseline: 1.5849x; 1.5849x over previous
//
#include <hip/hip_runtime.h>
#include <math.h>

#define NTHR 512
typedef unsigned long long u64;

// ---------------------------------------------------------------- helpers
__device__ __forceinline__ void st_uc(float* p, float v) {
    asm volatile("global_store_dword %0, %1, off sc0 sc1" :: "v"(p), "v"(v) : "memory");
}
#define LGKM0_BAR do { \
    asm volatile("s_waitcnt lgkmcnt(0)" ::: "memory"); \
    __builtin_amdgcn_s_barrier(); \
} while (0)

// ---------------------------------------------------------------- init
// hp/gp: 2 slots x 32 batches x 1024 cols of (step:u32 | value:f32) pairs.
// hp counter 0xFFFFFFFF = expected at k=0 (value 0 = h(-1)); gp never-match.
__global__ void init_kernel(u64* hp, u64* gp) {
    int i = blockIdx.x * blockDim.x + threadIdx.x;
    if (i < 65536) {
        __hip_atomic_store(hp + i, 0xFFFFFFFF00000000ull, __ATOMIC_RELAXED, __HIP_MEMORY_SCOPE_AGENT);
        __hip_atomic_store(gp + i, 0xFFFFFFFE00000000ull, __ATOMIC_RELAXED, __HIP_MEMORY_SCOPE_AGENT);
    }
}

// ---------------------------------------------------------------- xb = x @ b
__global__ __launch_bounds__(256) void xb_gemm(const float* __restrict__ X,
                                               const float* __restrict__ Bw,
                                               float* __restrict__ XB) {
    __shared__ float xs[16][132];
    __shared__ float bs[16][132];
    const int bm = blockIdx.x >> 3;
    const int bn = blockIdx.x & 7;
    const int m0 = bm * 128, n0 = bn * 128;
    const int tid = threadIdx.x;
    const int tx = tid & 15, ty = tid >> 4;
    float acc[8][8];
#pragma unroll
    for (int i = 0; i < 8; ++i)
#pragma unroll
        for (int j = 0; j < 8; ++j) acc[i][j] = 0.f;

    for (int k0 = 0; k0 < 1024; k0 += 16) {
#pragma unroll
        for (int p = 0; p < 2; ++p) {
            int f = tid + p * 256;
            int m = f >> 2, kq = f & 3;
            float4 v = *(const float4*)&X[(size_t)(m0 + m) * 1024 + k0 + kq * 4];
            xs[kq * 4 + 0][m] = v.x; xs[kq * 4 + 1][m] = v.y;
            xs[kq * 4 + 2][m] = v.z; xs[kq * 4 + 3][m] = v.w;
        }
#pragma unroll
        for (int p = 0; p < 2; ++p) {
            int f = tid + p * 256;
            int k = f >> 5, n = (f & 31) * 4;
            float4 v = *(const float4*)&Bw[(size_t)(k0 + k) * 1024 + n0 + n];
            *(float4*)&bs[k][n] = v;
        }
        __syncthreads();
#pragma unroll
        for (int k = 0; k < 16; ++k) {
            float xv[8], bv[8];
            *(float4*)&xv[0] = *(const float4*)&xs[k][ty * 8];
            *(float4*)&xv[4] = *(const float4*)&xs[k][ty * 8 + 4];
            *(float4*)&bv[0] = *(const float4*)&bs[k][tx * 8];
            *(float4*)&bv[4] = *(const float4*)&bs[k][tx * 8 + 4];
#pragma unroll
            for (int i = 0; i < 8; ++i)
#pragma unroll
                for (int j = 0; j < 8; ++j) acc[i][j] += xv[i] * bv[j];
        }
        __syncthreads();
    }
#pragma unroll
    for (int i = 0; i < 8; ++i)
#pragma unroll
        for (int j = 0; j < 8; j += 4) {
            float4 v = make_float4(acc[i][j], acc[i][j + 1], acc[i][j + 2], acc[i][j + 3]);
            *(float4*)&XB[(size_t)(m0 + ty * 8 + i) * 1024 + n0 + tx * 8 + j] = v;
        }
}

// ---------------------------------------------------------------- persistent scan
// 256 WGs = 2 streams x 4 bg(4 batches) x 64 slices. In-band (value,step) pairs
// (r10/r11, proven). r13 change vs r11: prefetch issued right AFTER B1 (not
// after compute) -> in-flight window = compute+B2+epi (~1us) covers the LLC
// RTT with ~1.3us of producer-skew tolerance. Everything else identical.
__global__ __launch_bounds__(NTHR, 1) void scan_kernel(
    const float* __restrict__ A, const float* __restrict__ CTm,
    float* __restrict__ XBH, u64* __restrict__ hp, u64* __restrict__ gp,
    float* __restrict__ ht_out, float* __restrict__ ct_out) {
    extern __shared__ float lds[];
    float* a_lf  = lds;                    // 16384 floats (64KB)
    float* ct_lf = lds + 16384;            // 16384 floats (64KB)
    float* stgf  = lds + 32768;            // 4096 floats (16KB), shared by streams
    float* scr0  = lds + 36864;            // 256 floats
    float* scr1  = lds + 37120;            // 256 floats  (149504 B total)
    const float4* a_l4  = (const float4*)a_lf;
    const float4* ct_l4 = (const float4*)ct_lf;
    float4* stg4 = (float4*)stgf;

    const int wg  = blockIdx.x;
    const int bg0 = wg >> 6;               // 0..3
    const int bg1 = bg0 + 4;               // 4..7
    const int sg  = wg & 63;
    const int c0wg = sg * 16;
    const int tid = threadIdx.x;

    // ---- one-time weight preload: cols c0wg..c0wg+15, col-major ----
    {
        const int c = tid & 15, i0 = tid >> 4;
        for (int i = i0; i < 1024; i += 32) {
            a_lf[c * 1024 + i]  = A[(size_t)i * 1024 + c0wg + c];
            ct_lf[c * 1024 + i] = CTm[(size_t)i * 1024 + c0wg + c];
        }
    }

    const int L  = tid & 63;
    const int w  = tid >> 6;
    const int Lc = L & 7;
    const int Lb = (L >> 3) & 3;
    const int cg = w & 1, kq = w >> 1;

    int wIdx[8], sIdx[4];
#pragma unroll
    for (int c = 0; c < 8; ++c) wIdx[c] = (cg * 8 + (c ^ Lc)) * 256 + kq * 64 + L;
#pragma unroll
    for (int r = 0; r < 4; ++r) sIdx[r] = ((r ^ Lb) << 8) + kq * 64 + L;

    // epilogue lane mapping: 1 output/lane (4 batches x 16 cols)
    const int e_b   = L >> 4;
    const int e_j   = L & 15;
    const int e_cgo = e_j >> 3;
    const int e_sx  = e_b * 8 + (e_j & 7);
    const int col   = c0wg + e_j;

    float creg = 0.f;                      // stream0 cell in w0, stream1 in w4
    float xbv  = 0.f;                      // stream0 xb in w1, stream1 in w2
    u64 qpf[8];                            // prefetched pairs for next sub-phase

    auto issue_pf = [&](const u64* base) {
#pragma unroll
        for (int j = 0; j < 8; ++j)
            qpf[j] = __hip_atomic_load(base + tid + 512 * j, __ATOMIC_RELAXED,
                                       __HIP_MEMORY_SCOPE_AGENT);
    };

    auto compute = [&](const float4* wmat, float* scr) {
        float4 sv[4], wv[8];
#pragma unroll
        for (int r = 0; r < 4; ++r) sv[r] = stg4[sIdx[r]];
#pragma unroll
        for (int c = 0; c < 8; ++c) wv[c] = wmat[wIdx[c]];
        float v[32];
#pragma unroll
        for (int r = 0; r < 4; ++r)
#pragma unroll
            for (int c = 0; c < 8; ++c)
                v[r * 8 + c] = sv[r].x * wv[c].x + sv[r].y * wv[c].y
                             + sv[r].z * wv[c].z + sv[r].w * wv[c].w;
#pragma unroll
        for (int j = 0; j < 16; ++j) v[j] = v[2 * j] + __shfl_xor(v[2 * j + 1], 1);
#pragma unroll
        for (int j = 0; j < 8; ++j)  v[j] = v[2 * j] + __shfl_xor(v[2 * j + 1], 2);
#pragma unroll
        for (int j = 0; j < 4; ++j)  v[j] = v[2 * j] + __shfl_xor(v[2 * j + 1], 4);
#pragma unroll
        for (int j = 0; j < 2; ++j)  v[j] = v[2 * j] + __shfl_xor(v[2 * j + 1], 8);
        v[0] = v[0] + __shfl_xor(v[1], 16);
        v[0] = v[0] + __shfl_xor(v[0], 32);
        if (L < 32) scr[kq * 64 + cg * 32 + L] = v[0];
    };

    auto epiA_fn = [&](int t, const float* s, int bgx) {      // g = (h@A)*xb
        float q = s[e_cgo * 32 + e_sx] + s[64 + e_cgo * 32 + e_sx]
                + s[128 + e_cgo * 32 + e_sx] + s[192 + e_cgo * 32 + e_sx];
        u64 pk = ((u64)(unsigned)t << 32) | (u64)__float_as_uint(q * xbv);
        __hip_atomic_store(gp + (size_t)(t & 1) * 32768 + (size_t)(bgx * 4 + e_b) * 1024 + col,
                           pk, __ATOMIC_RELAXED, __HIP_MEMORY_SCOPE_AGENT);
    };
    auto epiB_fn = [&](int t, const float* s, int bgx) {      // gates + cell
        float q0 = s[e_cgo * 32 + e_sx],       q1 = s[64 + e_cgo * 32 + e_sx];
        float q2 = s[128 + e_cgo * 32 + e_sx], q3 = s[192 + e_cgo * 32 + e_sx];
        float ft = 1.f / (1.f + __expf(-q0));
        float it = 1.f / (1.f + __expf(-q1));
        float gt = tanhf(q2);
        float ot = 1.f / (1.f + __expf(-q3));
        creg = ft * creg + it * gt;
        float hv = ot * tanhf(creg);
        int bglob = bgx * 4 + e_b;
        u64 pk = ((u64)(unsigned)t << 32) | (u64)__float_as_uint(hv);
        __hip_atomic_store(hp + (size_t)(t & 1) * 32768 + (size_t)bglob * 1024 + col,
                           pk, __ATOMIC_RELAXED, __HIP_MEMORY_SCOPE_AGENT);
        st_uc(XBH + ((size_t)bglob * 512 + t) * 1024 + col, hv);
        if (t == 511) {
            st_uc(ht_out + (size_t)bglob * 1024 + col, hv);
            st_uc(ct_out + (size_t)bglob * 1024 + col, creg);
        }
    };

    // sub-phase: pending epi -> validate prefetched pairs -> stage -> B1 ->
    // issue prefetch(next) -> compute -> B2. Raw barriers: no vmcnt drain.
    auto sub = [&](const u64* base, unsigned expect, const float4* wmat, float* scr,
                   int ek, int t, const u64* pfbase) {
        if (ek == 1) { if (w == 4 && t > 0) epiB_fn(t - 1, scr1, bg1); }
        else if (ek == 2) { if (w == 1) epiA_fn(t, scr0, bg0); }
        else if (ek == 3) { if (w == 2) epiA_fn(t, scr1, bg1); }
        else { if (w == 0) epiB_fn(t, scr0, bg0); }
        u64 q[8];
#pragma unroll
        for (int j = 0; j < 8; ++j) q[j] = qpf[j];
        for (;;) {
            bool ok = true;
#pragma unroll
            for (int j = 0; j < 8; ++j) ok &= ((unsigned)(q[j] >> 32) == expect);
            if (!__any(!ok)) break;
            __builtin_amdgcn_s_sleep(1);
#pragma unroll
            for (int j = 0; j < 8; ++j)
                q[j] = __hip_atomic_load(base + tid + 512 * j, __ATOMIC_RELAXED,
                                         __HIP_MEMORY_SCOPE_AGENT);
        }
#pragma unroll
        for (int j = 0; j < 8; ++j) stgf[tid + 512 * j] = __uint_as_float((unsigned)q[j]);
        LGKM0_BAR;                         // B1: staged
        issue_pf(pfbase);                  // in flight across compute + B2 + next epi
        compute(wmat, scr);
        LGKM0_BAR;                         // B2: scr ready, staging consumed
    };

    __syncthreads();                       // weights ready (one-time, full drain ok)
    issue_pf(hp + 32768 + (size_t)bg0 * 4096);   // prologue: A0(0) pairs (slot 1)

    for (int k = 0; k < 512; ++k) {
        const unsigned expA = (unsigned)(k - 1);
        const unsigned expB = (unsigned)k;
        // xb for this iter's A-epilogues (in flight until epiA consumes)
        if (w == 1) xbv = __uint_as_float(__hip_atomic_load(
            (const unsigned*)(XBH + ((size_t)(bg0 * 4 + e_b) * 512 + k) * 1024 + col),
            __ATOMIC_RELAXED, __HIP_MEMORY_SCOPE_AGENT));
        if (w == 2) xbv = __uint_as_float(__hip_atomic_load(
            (const unsigned*)(XBH + ((size_t)(bg1 * 4 + e_b) * 512 + k) * 1024 + col),
            __ATOMIC_RELAXED, __HIP_MEMORY_SCOPE_AGENT));

        const size_t hsl = (size_t)((k + 1) & 1) * 32768;
        const size_t gsl = (size_t)(k & 1) * 32768;
        // A0(k): consume h0(k-1); pending epiB1(k-1); prefetch A1 = h1(k-1)
        sub(hp + hsl + (size_t)bg0 * 4096, expA, a_l4, scr0, 1, k,
            hp + hsl + (size_t)bg1 * 4096);
        // A1(k): consume h1(k-1); pending epiA0(k); prefetch B0 = g0(k)
        sub(hp + hsl + (size_t)bg1 * 4096, expA, a_l4, scr1, 2, k,
            gp + gsl + (size_t)bg0 * 4096);
        // B0(k): consume g0(k); pending epiA1(k); prefetch B1 = g1(k)
        sub(gp + gsl + (size_t)bg0 * 4096, expB, ct_l4, scr0, 3, k,
            gp + gsl + (size_t)bg1 * 4096);
        // B1(k): consume g1(k); pending epiB0(k); prefetch A0(k+1) = h0(k)
        sub(gp + gsl + (size_t)bg1 * 4096, expB, ct_l4, scr1, 4, k,
            hp + (size_t)(k & 1) * 32768 + (size_t)bg0 * 4096);
    }
    // tail: epiB1(511) (scr1 from B1(511), ordered by its B2)
    if (w == 4) epiB_fn(511, scr1, bg1);
}

// ---------------------------------------------------------------- launch
extern "C" void kernel_launch(void* const* d_in, const int* in_sizes, int n_in,
                              void* d_out, int out_size, void* d_ws, size_t ws_size,
                              hipStream_t stream) {
    const float* X   = (const float*)d_in[0];
    const float* A   = (const float*)d_in[1];
    const float* Bw  = (const float*)d_in[2];
    const float* CTm = (const float*)d_in[3];

    float* out    = (float*)d_out;
    float* XBH    = out;                                  // xb in, hidden_seq out
    float* ht_out = out + (size_t)32 * 512 * 1024;
    float* ct_out = ht_out + 32 * 1024;

    u64* hp = (u64*)d_ws;                                 // 65536 pairs (512KB)
    u64* gp = hp + 65536;                                 // 65536 pairs (512KB)

    (void)hipFuncSetAttribute((const void*)scan_kernel,
                              hipFuncAttributeMaxDynamicSharedMemorySize, 149504);

    init_kernel<<<dim3(256), dim3(256), 0, stream>>>(hp, gp);
    xb_gemm<<<dim3(1024), dim3(256), 0, stream>>>(X, Bw, XBH);
    scan_kernel<<<dim3(256), dim3(NTHR), 149504, stream>>>(A, CTm, XBH, hp, gp,
                                                           ht_out, ct_out);
}